// Round 1
// baseline (249.529 us; speedup 1.0000x reference)
//
#include <hip/hip_runtime.h>

// TBSyntaxParser: B=8192 states, L=128, H=50.
// Per state: gather 3 consecutive buffer rows (at buffer_index) + 3 stack rows,
// X[300] = concat, out[3] = legal * exp(clip(X @ W.T + b, -1e6, 10)).
//
// One wave (64 lanes) per state; 4 waves per 256-thread block -> 2048 blocks.
// X walked as 150 float2 (rows are 200 B => 8-B aligned). The 3 buffer rows are
// contiguous in memory (consecutive indices) => one 75-float2 contiguous region.

constexpr int Bn = 8192;
constexpr int Ln = 128;
constexpr int Hn = 50;           // floats per row
constexpr int H2 = Hn / 2;       // 25 float2 per row
constexpr int K  = 6 * Hn;       // 300 = X length in floats
constexpr int K2 = K / 2;        // 150 float2

__global__ __launch_bounds__(256) void TBSyntaxParser_kernel(
    const float* __restrict__ buffer,   // [B, L, H]
    const float* __restrict__ W,        // [3, 300]
    const float* __restrict__ bvec,     // [3]
    const float* __restrict__ legal,    // [B, 3]
    const int*   __restrict__ buf_idx,  // [B]
    const int*   __restrict__ stk_idx,  // [B, 3]
    float*       __restrict__ out)      // [B, 3]
{
    const int lane  = threadIdx.x & 63;
    const int state = blockIdx.x * 4 + (threadIdx.x >> 6);

    const float* bufb = buffer + (size_t)state * (Ln * Hn);
    const int bi = buf_idx[state];
    const int s0 = stk_idx[state * 3 + 0];
    const int s1 = stk_idx[state * 3 + 1];
    const int s2 = stk_idx[state * 3 + 2];

    // Contiguous 75-float2 region covering the 3 consecutive buffer rows.
    const float2* bufs2 = (const float2*)(bufb + bi * Hn);
    const float2* W2    = (const float2*)W;

    float acc0 = 0.f, acc1 = 0.f, acc2 = 0.f;

#pragma unroll
    for (int it = 0; it < 3; ++it) {
        const int e = lane + it * 64;      // float2 index into X, [0, 150)
        if (e < K2) {
            float2 x;
            if (e < 75) {
                x = bufs2[e];
            } else {
                const int ee  = e - 75;
                const int r   = ee / H2;          // 0..2
                const int pos = ee - r * H2;      // 0..24
                const int row = (r == 0) ? s0 : ((r == 1) ? s1 : s2);
                x = ((const float2*)(bufb + row * Hn))[pos];
            }
            const float2 w0 = W2[e];
            const float2 w1 = W2[K2 + e];
            const float2 w2 = W2[2 * K2 + e];
            acc0 += x.x * w0.x + x.y * w0.y;
            acc1 += x.x * w1.x + x.y * w1.y;
            acc2 += x.x * w2.x + x.y * w2.y;
        }
    }

    // Wave-64 butterfly reduction.
#pragma unroll
    for (int off = 32; off > 0; off >>= 1) {
        acc0 += __shfl_down(acc0, off, 64);
        acc1 += __shfl_down(acc1, off, 64);
        acc2 += __shfl_down(acc2, off, 64);
    }

    if (lane == 0) {
        const float b0 = bvec[0], b1 = bvec[1], b2 = bvec[2];
        float r0 = fminf(fmaxf(acc0 + b0, -1e6f), 10.0f);
        float r1 = fminf(fmaxf(acc1 + b1, -1e6f), 10.0f);
        float r2 = fminf(fmaxf(acc2 + b2, -1e6f), 10.0f);
        r0 = __expf(r0) * legal[state * 3 + 0];
        r1 = __expf(r1) * legal[state * 3 + 1];
        r2 = __expf(r2) * legal[state * 3 + 2];
        out[state * 3 + 0] = r0;
        out[state * 3 + 1] = r1;
        out[state * 3 + 2] = r2;
    }
}

extern "C" void kernel_launch(void* const* d_in, const int* in_sizes, int n_in,
                              void* d_out, int out_size, void* d_ws, size_t ws_size,
                              hipStream_t stream) {
    const float* buffer  = (const float*)d_in[0];
    const float* W       = (const float*)d_in[1];
    const float* bvec    = (const float*)d_in[2];
    const float* legal   = (const float*)d_in[3];
    const int*   buf_idx = (const int*)d_in[4];
    const int*   stk_idx = (const int*)d_in[5];
    float* out = (float*)d_out;

    // 1 wave per state, 4 waves per block -> 8192/4 = 2048 blocks.
    TBSyntaxParser_kernel<<<Bn / 4, 256, 0, stream>>>(
        buffer, W, bvec, legal, buf_idx, stk_idx, out);
}

// Round 2
// 248.048 us; speedup vs baseline: 1.0060x; 1.0060x over previous
//
#include <hip/hip_runtime.h>

// TBSyntaxParser: B=8192 states, L=128, H=50.
// Per state: gather 3 consecutive buffer rows (at buffer_index) + 3 stack rows,
// X[300] = concat, out[3] = legal * exp(clip(X @ W.T + b, -1e6, 10)).
//
// One wave (64 lanes) per state; 4 waves per 256-thread block -> 2048 blocks.
// X walked as 150 float2 (rows are 200 B => 8-B aligned; float4 would be
// misaligned for odd rows). The 3 buffer rows are contiguous in memory
// (consecutive indices) => one 75-float2 contiguous region.
//
// R2: branch-free iterations 0/1 (e<128 always valid), masked tail only for
// it=2; explicit fmaf; legal[] loaded before the reduction to overlap latency;
// 3-lane coalesced store of out[3].

constexpr int Bn = 8192;
constexpr int Ln = 128;
constexpr int Hn = 50;           // floats per row
constexpr int H2 = Hn / 2;       // 25 float2 per row
constexpr int K2 = 150;          // float2 elements in X

__global__ __launch_bounds__(256) void TBSyntaxParser_kernel(
    const float* __restrict__ buffer,   // [B, L, H]
    const float* __restrict__ W,        // [3, 300]
    const float* __restrict__ bvec,     // [3]
    const float* __restrict__ legal,    // [B, 3]
    const int*   __restrict__ buf_idx,  // [B]
    const int*   __restrict__ stk_idx,  // [B, 3]
    float*       __restrict__ out)      // [B, 3]
{
    const int lane  = threadIdx.x & 63;
    const int state = blockIdx.x * 4 + (threadIdx.x >> 6);

    const float* bufb = buffer + (size_t)state * (Ln * Hn);
    const int bi = buf_idx[state];
    const int s0 = stk_idx[state * 3 + 0];
    const int s1 = stk_idx[state * 3 + 1];
    const int s2 = stk_idx[state * 3 + 2];

    // Load legality mask early (lanes 0-2) so its latency overlaps the math.
    float my_legal = 0.f;
    if (lane < 3) my_legal = legal[state * 3 + lane];

    const float2* bufs2 = (const float2*)(bufb + bi * Hn);  // 75 contiguous float2
    const float2* W2    = (const float2*)W;

    float acc0 = 0.f, acc1 = 0.f, acc2 = 0.f;

    // Helper lambda: accumulate element e of X against all 3 weight rows.
    auto accum = [&](int e, float2 x) {
        const float2 w0 = W2[e];
        const float2 w1 = W2[K2 + e];
        const float2 w2 = W2[2 * K2 + e];
        acc0 = fmaf(x.x, w0.x, fmaf(x.y, w0.y, acc0));
        acc1 = fmaf(x.x, w1.x, fmaf(x.y, w1.y, acc1));
        acc2 = fmaf(x.x, w2.x, fmaf(x.y, w2.y, acc2));
    };

    // it = 0: e = lane in [0,64)  -> always buffer-region (e < 75).
    {
        const int e = lane;
        accum(e, bufs2[e]);
    }
    // it = 1: e = lane + 64 in [64,128) -> mixed buffer/stack, always valid.
    {
        const int e = lane + 64;
        float2 x;
        if (e < 75) {
            x = bufs2[e];
        } else {
            const int ee  = e - 75;
            const int r   = ee / H2;
            const int pos = ee - r * H2;
            const int row = (r == 0) ? s0 : ((r == 1) ? s1 : s2);
            x = ((const float2*)(bufb + row * Hn))[pos];
        }
        accum(e, x);
    }
    // it = 2: e = lane + 128 in [128,192) -> valid only for e < 150 (stack rows).
    if (lane < 22) {
        const int e   = lane + 128;
        const int ee  = e - 75;
        const int r   = ee / H2;
        const int pos = ee - r * H2;
        const int row = (r == 0) ? s0 : ((r == 1) ? s1 : s2);
        accum(e, ((const float2*)(bufb + row * Hn))[pos]);
    }

    // Wave-64 butterfly reduction.
#pragma unroll
    for (int off = 32; off > 0; off >>= 1) {
        acc0 += __shfl_down(acc0, off, 64);
        acc1 += __shfl_down(acc1, off, 64);
        acc2 += __shfl_down(acc2, off, 64);
    }

    // Lane r (r=0..2) takes acc_r from lane 0's registers via broadcast shuffles.
    const float a0 = __shfl(acc0, 0, 64);
    const float a1 = __shfl(acc1, 0, 64);
    const float a2 = __shfl(acc2, 0, 64);

    if (lane < 3) {
        const float a  = (lane == 0) ? a0 : ((lane == 1) ? a1 : a2);
        const float bb = bvec[lane];
        float r = fminf(fmaxf(a + bb, -1e6f), 10.0f);
        out[state * 3 + lane] = __expf(r) * my_legal;
    }
}

extern "C" void kernel_launch(void* const* d_in, const int* in_sizes, int n_in,
                              void* d_out, int out_size, void* d_ws, size_t ws_size,
                              hipStream_t stream) {
    const float* buffer  = (const float*)d_in[0];
    const float* W       = (const float*)d_in[1];
    const float* bvec    = (const float*)d_in[2];
    const float* legal   = (const float*)d_in[3];
    const int*   buf_idx = (const int*)d_in[4];
    const int*   stk_idx = (const int*)d_in[5];
    float* out = (float*)d_out;

    TBSyntaxParser_kernel<<<Bn / 4, 256, 0, stream>>>(
        buffer, W, bvec, legal, buf_idx, stk_idx, out);
}